// Round 1
// baseline (4555.620 us; speedup 1.0000x reference)
//
#include <hip/hip_runtime.h>

#define T_STEPS 2048
#define BATCH   64
#define IN_DIM  256
#define HID     512

typedef _Float16 half_t;
typedef half_t half2_t __attribute__((ext_vector_type(2)));

#if __has_builtin(__builtin_amdgcn_fdot2)
__device__ __forceinline__ float fdot2(half2_t a, half2_t b, float c) {
    return __builtin_amdgcn_fdot2(a, b, c, false);   // v_dot2_f32_f16
}
#else
__device__ __forceinline__ float fdot2(half2_t a, half2_t b, float c) {
    return c + (float)a.x * (float)b.x + (float)a.y * (float)b.y;
}
#endif

// ---------------------------------------------------------------------------
// K1: x_proj[t*B+b][h] = input[t*B+b][i] @ w_in[i][h]
// M=131072, K=256, N=512, fp32. Tile 128x128, BK=32, 256 threads, 8x8 micro.
// Writes into d_out's hiddens region (consumed in-place by K2).
// ---------------------------------------------------------------------------
__global__ __launch_bounds__(256, 4)
void xproj_gemm(const float* __restrict__ A, const float* __restrict__ Win,
                float* __restrict__ out) {
    __shared__ float As[32][132];   // [k][m], padded row stride 132 (16B aligned)
    __shared__ float Bs[32][132];   // [k][n]
    const int tid = threadIdx.x;
    const int m0 = blockIdx.y * 128;
    const int n0 = blockIdx.x * 128;
    const int tm = (tid >> 4) << 3;   // 0..120
    const int tn = (tid & 15) << 3;   // 0..120

    float acc[8][8] = {};

    for (int k0 = 0; k0 < IN_DIM; k0 += 32) {
        // stage A tile (128x32), transposed into As[k][m]
        {
            const int m  = tid >> 3;          // 0..31
            const int k4 = (tid & 7) << 2;    // 0,4,...,28
#pragma unroll
            for (int r = 0; r < 4; ++r) {
                const float4 a4 = *(const float4*)&A[(size_t)(m0 + m + 32 * r) * IN_DIM + k0 + k4];
                As[k4 + 0][m + 32 * r] = a4.x;
                As[k4 + 1][m + 32 * r] = a4.y;
                As[k4 + 2][m + 32 * r] = a4.z;
                As[k4 + 3][m + 32 * r] = a4.w;
            }
        }
        // stage B tile (32x128)
        {
            const int kb = tid >> 5;            // 0..7
            const int n4 = (tid & 31) << 2;     // 0..124
#pragma unroll
            for (int r = 0; r < 4; ++r) {
                const float4 b4 = *(const float4*)&Win[(size_t)(k0 + kb + 8 * r) * HID + n0 + n4];
                *(float4*)&Bs[kb + 8 * r][n4] = b4;
            }
        }
        __syncthreads();
#pragma unroll
        for (int kk = 0; kk < 32; ++kk) {
            const float4 a0 = *(const float4*)&As[kk][tm];
            const float4 a1 = *(const float4*)&As[kk][tm + 4];
            const float4 b0 = *(const float4*)&Bs[kk][tn];
            const float4 b1 = *(const float4*)&Bs[kk][tn + 4];
            const float av[8] = {a0.x, a0.y, a0.z, a0.w, a1.x, a1.y, a1.z, a1.w};
            const float bv[8] = {b0.x, b0.y, b0.z, b0.w, b1.x, b1.y, b1.z, b1.w};
#pragma unroll
            for (int i = 0; i < 8; ++i)
#pragma unroll
                for (int j = 0; j < 8; ++j)
                    acc[i][j] = fmaf(av[i], bv[j], acc[i][j]);
        }
        __syncthreads();
    }

#pragma unroll
    for (int i = 0; i < 8; ++i) {
        float4 c0 = {acc[i][0], acc[i][1], acc[i][2], acc[i][3]};
        float4 c1 = {acc[i][4], acc[i][5], acc[i][6], acc[i][7]};
        float* dst = &out[(size_t)(m0 + tm + i) * HID + n0 + tn];
        *(float4*)dst       = c0;
        *(float4*)(dst + 4) = c1;
    }
}

// ---------------------------------------------------------------------------
// K2: sequential scan. 64 WGs (1 per batch row), 512 threads (8 waves).
// w_rec held on-CU as f16: thread (jg=tid&63, kg=tid>>6) owns cols
// [8*jg, 8*jg+8) x k-rows [64*kg, 64*kg+64): 48 rows in VGPRs (24 x v2f16
// per col = 192 regs), 16 rows in a 128KB LDS slab ([slot][tid] layout ->
// conflict-free b32 reads). h kept as packed f16 pairs in LDS; k-split groups
// are wave-aligned so h reads are wave-uniform broadcasts. Partial sums
// reduced through a skewed LDS buffer (9*jg+c indexing -> 2-way max).
// 2 barriers per step. fp32 accumulation throughout; tanh via v_exp_f32.
// ---------------------------------------------------------------------------
__global__ __launch_bounds__(512, 2)
void rnn_scan(const float* __restrict__ Wrec, float* __restrict__ out) {
    __shared__ half2_t WL[64 * 512];    // 128 KB: slot = c*8+p, addr slot*512+tid
    __shared__ half2_t h2buf[256];      // 1 KB: current h as f16 pairs
    __shared__ float   parts[8 * 640];  // 20 KB: [kg][9*jg + c] skewed

    const int tid   = threadIdx.x;
    const int b     = blockIdx.x;
    const int jg    = tid & 63;
    const int kg    = tid >> 6;          // == wave id (uniform per wave)
    const int col0  = jg << 3;           // 8 cols
    const int kbase = kg << 6;           // 64 k-rows

    // ---- load W: regs (k-rows kbase..kbase+48) + LDS (kbase+48..kbase+64)
    half2_t wreg[8][24];
#pragma unroll
    for (int p = 0; p < 24; ++p) {
        const int k = kbase + 2 * p;
        const float4 lo0 = *(const float4*)&Wrec[(size_t)k * HID + col0];
        const float4 lo1 = *(const float4*)&Wrec[(size_t)k * HID + col0 + 4];
        const float4 hi0 = *(const float4*)&Wrec[(size_t)(k + 1) * HID + col0];
        const float4 hi1 = *(const float4*)&Wrec[(size_t)(k + 1) * HID + col0 + 4];
        wreg[0][p].x = (half_t)lo0.x; wreg[0][p].y = (half_t)hi0.x;
        wreg[1][p].x = (half_t)lo0.y; wreg[1][p].y = (half_t)hi0.y;
        wreg[2][p].x = (half_t)lo0.z; wreg[2][p].y = (half_t)hi0.z;
        wreg[3][p].x = (half_t)lo0.w; wreg[3][p].y = (half_t)hi0.w;
        wreg[4][p].x = (half_t)lo1.x; wreg[4][p].y = (half_t)hi1.x;
        wreg[5][p].x = (half_t)lo1.y; wreg[5][p].y = (half_t)hi1.y;
        wreg[6][p].x = (half_t)lo1.z; wreg[6][p].y = (half_t)hi1.z;
        wreg[7][p].x = (half_t)lo1.w; wreg[7][p].y = (half_t)hi1.w;
    }
#pragma unroll
    for (int p = 0; p < 8; ++p) {
        const int k = kbase + 48 + 2 * p;
        const float4 lo0 = *(const float4*)&Wrec[(size_t)k * HID + col0];
        const float4 lo1 = *(const float4*)&Wrec[(size_t)k * HID + col0 + 4];
        const float4 hi0 = *(const float4*)&Wrec[(size_t)(k + 1) * HID + col0];
        const float4 hi1 = *(const float4*)&Wrec[(size_t)(k + 1) * HID + col0 + 4];
        half2_t w;
        w.x = (half_t)lo0.x; w.y = (half_t)hi0.x; WL[(0 * 8 + p) * 512 + tid] = w;
        w.x = (half_t)lo0.y; w.y = (half_t)hi0.y; WL[(1 * 8 + p) * 512 + tid] = w;
        w.x = (half_t)lo0.z; w.y = (half_t)hi0.z; WL[(2 * 8 + p) * 512 + tid] = w;
        w.x = (half_t)lo0.w; w.y = (half_t)hi0.w; WL[(3 * 8 + p) * 512 + tid] = w;
        w.x = (half_t)lo1.x; w.y = (half_t)hi1.x; WL[(4 * 8 + p) * 512 + tid] = w;
        w.x = (half_t)lo1.y; w.y = (half_t)hi1.y; WL[(5 * 8 + p) * 512 + tid] = w;
        w.x = (half_t)lo1.z; w.y = (half_t)hi1.z; WL[(6 * 8 + p) * 512 + tid] = w;
        w.x = (half_t)lo1.w; w.y = (half_t)hi1.w; WL[(7 * 8 + p) * 512 + tid] = w;
    }
    // h0 = 0
    if (tid < 256) { half2_t z; z.x = (half_t)0.f; z.y = (half_t)0.f; h2buf[tid] = z; }
    __syncthreads();

    const int jcol  = tid;                       // finalize column
    const int pbase = 9 * (jcol >> 3) + (jcol & 7);

    for (int t = 0; t < T_STEPS; ++t) {
        // prefetch xp (used only at finalize; stays in flight across the dots)
        const float xpv = out[((size_t)t * BATCH + b) * HID + jcol];

        float acc[8] = {};
#pragma unroll
        for (int p = 0; p < 24; ++p) {
            const half2_t hv = h2buf[kg * 32 + p];       // wave-uniform broadcast
#pragma unroll
            for (int c = 0; c < 8; ++c)
                acc[c] = fdot2(wreg[c][p], hv, acc[c]);
        }
#pragma unroll
        for (int p = 0; p < 8; ++p) {
            const half2_t hv = h2buf[kg * 32 + 24 + p];
#pragma unroll
            for (int c = 0; c < 8; ++c)
                acc[c] = fdot2(WL[(c * 8 + p) * 512 + tid], hv, acc[c]);
        }
#pragma unroll
        for (int c = 0; c < 8; ++c)
            parts[kg * 640 + 9 * jg + c] = acc[c];
        __syncthreads();

        // finalize column jcol: sum 8 partials, add xp, tanh
        float s = xpv;
#pragma unroll
        for (int g = 0; g < 8; ++g)
            s += parts[g * 640 + pbase];
        const float e  = __expf(2.0f * s);
        const float hj = 1.0f - 2.0f / (e + 1.0f);     // tanh(s), saturates correctly

        out[((size_t)t * BATCH + b) * HID + jcol] = hj;
        if (t == T_STEPS - 1)
            out[(size_t)T_STEPS * BATCH * HID + (size_t)b * HID + jcol] = hj;

        ((half_t*)h2buf)[jcol] = (half_t)hj;
        __syncthreads();
    }
}

extern "C" void kernel_launch(void* const* d_in, const int* in_sizes, int n_in,
                              void* d_out, int out_size, void* d_ws, size_t ws_size,
                              hipStream_t stream) {
    const float* A    = (const float*)d_in[0];   // [T,B,I]
    const float* Win  = (const float*)d_in[1];   // [I,H]
    const float* Wrec = (const float*)d_in[2];   // [H,H]
    float* out = (float*)d_out;                  // [T,B,H] hiddens ++ [B,H] h_last

    dim3 g1(HID / 128, (T_STEPS * BATCH) / 128); // (4, 1024)
    xproj_gemm<<<g1, 256, 0, stream>>>(A, Win, out);
    rnn_scan<<<BATCH, 512, 0, stream>>>(Wrec, out);
}